// Round 11
// baseline (222.594 us; speedup 1.0000x reference)
//
#include <hip/hip_runtime.h>
#include <stdint.h>

#define NEG_INF (-__builtin_inff())
#define L2E 1.4426950408889634f

namespace {
constexpr int kT   = 1024;
constexpr int kE   = 2048;
}

using bf16x8 = __attribute__((ext_vector_type(8))) short;
using f32x4  = __attribute__((ext_vector_type(4))) float;
using i32x4  = __attribute__((ext_vector_type(4))) int;
using i32x16 = __attribute__((ext_vector_type(16))) int;

#define MFMA_BF16(a, b, c) __builtin_amdgcn_mfma_f32_16x16x32_bf16((a), (b), (c), 0, 0, 0)
#define MFMA_I8_32(a, b, c) __builtin_amdgcn_mfma_i32_32x32x32_i8((a), (b), (c), 0, 0, 0)

// ---------------- small helpers ----------------
__device__ __forceinline__ void gload16(const void* g, void* l) {
  __builtin_amdgcn_global_load_lds((const __attribute__((address_space(1))) unsigned*)g,
                                   (__attribute__((address_space(3))) unsigned*)l, 16, 0, 0);
}
__device__ __forceinline__ unsigned bfr(float x) {  // f32 -> bf16 bits (RNE)
  unsigned u = __float_as_uint(x);
  return (u + 0x7FFFu + ((u >> 16) & 1u)) >> 16;
}
__device__ __forceinline__ float bf2f(unsigned h) { return __uint_as_float(h << 16); }
__device__ __forceinline__ unsigned pk2(float a, float b) { return bfr(a) | (bfr(b) << 16); }
__device__ __forceinline__ float fexp2(float x) { return __builtin_amdgcn_exp2f(x); }

__device__ __forceinline__ float waveReduceMax(float v) {
#pragma unroll
  for (int o = 32; o > 0; o >>= 1) v = fmaxf(v, __shfl_down(v, o, 64));
  return v;
}
__device__ __forceinline__ float blockMax256(float v, float* r4) {
  const int tid = threadIdx.x;
  float wm = waveReduceMax(v);
  if ((tid & 63) == 0) r4[tid >> 6] = wm;
  __syncthreads();
  float bm = fmaxf(fmaxf(r4[0], r4[1]), fmaxf(r4[2], r4[3]));
  __syncthreads();
  return bm;
}

// ---------------- fused row-quant: hs + 4 weights (grid 2048 x 5) ----------------
__global__ __launch_bounds__(256) void k_rowquant_all(const float* __restrict__ Xh,
                                                      const float* __restrict__ W0,
                                                      const float* __restrict__ W1,
                                                      const float* __restrict__ W2,
                                                      const float* __restrict__ W3,
                                                      int8_t* __restrict__ Qh,
                                                      int8_t* __restrict__ Q0,
                                                      int8_t* __restrict__ Q1,
                                                      int8_t* __restrict__ Q2,
                                                      int8_t* __restrict__ Q3,
                                                      float* __restrict__ sX,
                                                      float* __restrict__ sWall,
                                                      unsigned* __restrict__ vmax) {
  const int y = blockIdx.y;
  const float* X = (y == 0) ? Xh : (y == 1) ? W0 : (y == 2) ? W1 : (y == 3) ? W2 : W3;
  int8_t* Qp = (y == 0) ? Qh : (y == 1) ? Q0 : (y == 2) ? Q1 : (y == 3) ? Q2 : Q3;
  const int row = blockIdx.x;
  const int tid = threadIdx.x;
  if (row == 0 && y == 0 && tid == 0) *vmax = 0u;
  const float* x = X + (size_t)row * kE;
  __shared__ float r4[4];
  float am = 0.f;
  float4 v[2];
#pragma unroll
  for (int it = 0; it < 2; ++it) {
    v[it] = *reinterpret_cast<const float4*>(x + (size_t)(it * 256 + tid) * 4);
    am = fmaxf(am, fmaxf(fmaxf(fabsf(v[it].x), fabsf(v[it].y)), fmaxf(fabsf(v[it].z), fabsf(v[it].w))));
  }
  const float bm = blockMax256(am, r4);
  const float s = fmaxf(bm, 1e-5f) / 127.f;
  int8_t* xq = Qp + (size_t)row * kE;
#pragma unroll
  for (int it = 0; it < 2; ++it) {
    const int i = (it * 256 + tid) * 4;
    char4 q;
    q.x = (char)(int)rintf(v[it].x / s);
    q.y = (char)(int)rintf(v[it].y / s);
    q.z = (char)(int)rintf(v[it].z / s);
    q.w = (char)(int)rintf(v[it].w / s);
    *reinterpret_cast<char4*>(xq + i) = q;
  }
  if (tid == 0) {
    if (y == 0) sX[row] = s;
    else sWall[(y - 1) * kE + row] = s;
  }
}

// final-context row quant
__global__ __launch_bounds__(256) void k_rowquant_i8(const float* __restrict__ X,
                                                     int8_t* __restrict__ Xq,
                                                     float* __restrict__ S) {
  const int row = blockIdx.x;
  const int tid = threadIdx.x;
  const float* x = X + (size_t)row * kE;
  __shared__ float r4[4];
  float am = 0.f;
  float4 v[2];
#pragma unroll
  for (int it = 0; it < 2; ++it) {
    v[it] = *reinterpret_cast<const float4*>(x + (size_t)(it * 256 + tid) * 4);
    am = fmaxf(am, fmaxf(fmaxf(fabsf(v[it].x), fabsf(v[it].y)), fmaxf(fabsf(v[it].z), fabsf(v[it].w))));
  }
  const float bm = blockMax256(am, r4);
  const float s = fmaxf(bm, 1e-5f) / 127.f;
  int8_t* xq = Xq + (size_t)row * kE;
#pragma unroll
  for (int it = 0; it < 2; ++it) {
    const int i = (it * 256 + tid) * 4;
    char4 q;
    q.x = (char)(int)rintf(v[it].x / s);
    q.y = (char)(int)rintf(v[it].y / s);
    q.z = (char)(int)rintf(v[it].z / s);
    q.w = (char)(int)rintf(v[it].w / s);
    *reinterpret_cast<char4*>(xq + i) = q;
  }
  if (tid == 0) S[row] = s;
}

// ---------------- fused prep: q->int-bf16, k->hi/lo split + scales, v absmax ----------------
__global__ __launch_bounds__(256) void k_prep(const float* __restrict__ Qb,
                                              const float* __restrict__ Kb,
                                              const float* __restrict__ Vb,
                                              short* __restrict__ qi,
                                              float* __restrict__ sqg,
                                              short* __restrict__ khi,
                                              short* __restrict__ klo,
                                              float* __restrict__ s4,
                                              float* __restrict__ smix,
                                              unsigned* __restrict__ vmax) {
  const int row = blockIdx.x;
  const int tid = threadIdx.x;
  __shared__ float r4[4];

  {
    const float* x = Qb + (size_t)row * kE;
    float am = 0.f;
    float4 v[2];
#pragma unroll
    for (int it = 0; it < 2; ++it) {
      v[it] = *reinterpret_cast<const float4*>(x + (size_t)(it * 256 + tid) * 4);
      am = fmaxf(am, fmaxf(fmaxf(fabsf(v[it].x), fabsf(v[it].y)), fmaxf(fabsf(v[it].z), fabsf(v[it].w))));
    }
    const float bm = blockMax256(am, r4);
    const float s = fmaxf(bm, 1e-5f) / 127.f;
#pragma unroll
    for (int it = 0; it < 2; ++it) {
      const int i = (it * 256 + tid) * 4;
      short4 q;
      q.x = (short)bfr(rintf(v[it].x / s));
      q.y = (short)bfr(rintf(v[it].y / s));
      q.z = (short)bfr(rintf(v[it].z / s));
      q.w = (short)bfr(rintf(v[it].w / s));
      *reinterpret_cast<short4*>(qi + (size_t)row * kE + i) = q;
    }
    if (tid == 0) sqg[row] = s * 0.125f;
  }

  {
    const float* x = Kb + (size_t)row * kE;
    float am = 0.f;
    float4 v[2];
#pragma unroll
    for (int it = 0; it < 2; ++it) {
      v[it] = *reinterpret_cast<const float4*>(x + (size_t)(it * 256 + tid) * 4);
      am = fmaxf(am, fmaxf(fmaxf(fabsf(v[it].x), fabsf(v[it].y)), fmaxf(fabsf(v[it].z), fabsf(v[it].w))));
    }
    const float bm = blockMax256(am, r4);
#pragma unroll
    for (int it = 0; it < 2; ++it) {
      const int i = (it * 256 + tid) * 4;
      short4 hh, ll;
      unsigned hb;
      hb = bfr(v[it].x); hh.x = (short)hb; ll.x = (short)bfr(v[it].x - bf2f(hb));
      hb = bfr(v[it].y); hh.y = (short)hb; ll.y = (short)bfr(v[it].y - bf2f(hb));
      hb = bfr(v[it].z); hh.z = (short)hb; ll.z = (short)bfr(v[it].z - bf2f(hb));
      hb = bfr(v[it].w); hh.w = (short)hb; ll.w = (short)bfr(v[it].w - bf2f(hb));
      *reinterpret_cast<short4*>(khi + (size_t)row * kE + i) = hh;
      *reinterpret_cast<short4*>(klo + (size_t)row * kE + i) = ll;
    }
    if (tid == 0) {
      s4[row] = fmaxf(bm, 1e-5f) / 7.f;
      if (row < kT) smix[row] = fmaxf(bm / 127.f, 1e-5f);
    }
  }

  {
    const float* x = Vb + (size_t)row * kE;
    float am = 0.f;
#pragma unroll
    for (int it = 0; it < 2; ++it) {
      const float4 v = *reinterpret_cast<const float4*>(x + (size_t)(it * 256 + tid) * 4);
      am = fmaxf(am, fmaxf(fmaxf(fabsf(v.x), fabsf(v.y)), fmaxf(fabsf(v.z), fabsf(v.w))));
    }
    const float bm = blockMax256(am, r4);
    if (tid == 0) atomicMax(vmax, __float_as_uint(bm));
  }
}

// ---------------- merged kint (rows 0..2047) + vint (blocks 2048..3071) ----------------
__global__ __launch_bounds__(256) void k_kvint(const float* __restrict__ Kb,
                                               const float* __restrict__ s4,
                                               const float* __restrict__ smix,
                                               const int* __restrict__ sel,
                                               short* __restrict__ ki,
                                               float* __restrict__ skg,
                                               const float* __restrict__ Vb,
                                               const unsigned* __restrict__ vmax,
                                               short* __restrict__ vt) {
  const int bid = blockIdx.x;
  const int tid = threadIdx.x;
  if (bid < 2048) {
    const int row = bid;
    const int t = row & (kT - 1);
    const float s = sel[t] ? smix[t] : s4[row];
    const float* x = Kb + (size_t)row * kE;
#pragma unroll
    for (int it = 0; it < 2; ++it) {
      const int i = (it * 256 + tid) * 4;
      const float4 v = *reinterpret_cast<const float4*>(x + i);
      short4 q;
      q.x = (short)bfr(rintf(v.x / s));
      q.y = (short)bfr(rintf(v.y / s));
      q.z = (short)bfr(rintf(v.z / s));
      q.w = (short)bfr(rintf(v.w / s));
      *reinterpret_cast<short4*>(ki + (size_t)row * kE + i) = q;
    }
    if (tid == 0) skg[row] = s;
  } else {
    const int t = bid - 2048;
    const int tt = t & 15, bh = t >> 4;
    const int b = bh >> 5, h = bh & 31;
    const float sv = fmaxf(__uint_as_float(*vmax), 1e-5f) / 7.f;
    __shared__ short tr[64][80];
#pragma unroll
    for (int i = 0; i < 4; ++i) {
      const int e = i * 256 + tid;
      const int tok = e >> 4, d4 = (e & 15) * 4;
      const float4 v = *reinterpret_cast<const float4*>(
          &Vb[(size_t)(b * kT + tt * 64 + tok) * kE + h * 64 + d4]);
      tr[d4 + 0][tok] = (short)bfr(rintf(v.x / sv));
      tr[d4 + 1][tok] = (short)bfr(rintf(v.y / sv));
      tr[d4 + 2][tok] = (short)bfr(rintf(v.z / sv));
      tr[d4 + 3][tok] = (short)bfr(rintf(v.w / sv));
    }
    __syncthreads();
#pragma unroll
    for (int i = 0; i < 2; ++i) {
      const int e = i * 256 + tid;
      const int d = e >> 3, u = e & 7;
      const bf16x8 row = *reinterpret_cast<const bf16x8*>(&tr[d][u * 8]);
      *reinterpret_cast<bf16x8*>(&vt[(size_t)(bh * 64 + d) * kT + tt * 64 + u * 8]) = row;
    }
  }
}

// ---------------- int8 MFMA GEMM body: 128x128 tile, 256 threads, 32x32x32 i8 ----------------
__device__ __forceinline__ void gemm_i8_body(int m0, int n0,
                                             const int8_t* __restrict__ A,
                                             const float* __restrict__ sa,
                                             const int8_t* __restrict__ Bw,
                                             const float* __restrict__ sw,
                                             const float* __restrict__ bias,
                                             float* __restrict__ Y,
                                             int8_t* AsBase, int8_t* BsBase) {
  const int tid = threadIdx.x;
  const int lane = tid & 63, w = tid >> 6;
  const int l31 = lane & 31, lh = lane >> 5;
  const int wm = (w >> 1) * 64, wn = (w & 1) * 64;

  const i32x16 zero16 = {0};
  i32x16 acc00 = zero16, acc01 = zero16, acc10 = zero16, acc11 = zero16;

  auto stage = [&](int buf, int k0) {
    int8_t* As = AsBase + buf * 8192;
    int8_t* Bs = BsBase + buf * 8192;
#pragma unroll
    for (int i = 0; i < 2; ++i) {
      const int s = i * 256 + tid;
      const int row = s >> 2, gp = s & 3;
      const int gs = gp ^ ((row >> 1) & 3);
      gload16(A + (size_t)(m0 + row) * kE + k0 + gs * 16, As + s * 16);
    }
#pragma unroll
    for (int i = 0; i < 2; ++i) {
      const int s = i * 256 + tid;
      const int row = s >> 2, gp = s & 3;
      const int gs = gp ^ ((row >> 1) & 3);
      gload16(Bw + (size_t)(n0 + row) * kE + k0 + gs * 16, Bs + s * 16);
    }
  };

  stage(0, 0);
  __syncthreads();
  int cur = 0;

  const int ar0 = wm + l31, ar1 = wm + 32 + l31;
  const int br0 = wn + l31, br1 = wn + 32 + l31;
  const int sa0 = (ar0 >> 1) & 3, sa1 = (ar1 >> 1) & 3;
  const int sb0 = (br0 >> 1) & 3, sb1 = (br1 >> 1) & 3;

  for (int k0 = 0; k0 < kE; k0 += 64) {
    if (k0 + 64 < kE) stage(cur ^ 1, k0 + 64);
    const int8_t* As = AsBase + cur * 8192;
    const int8_t* Bs = BsBase + cur * 8192;
#pragma unroll
    for (int j = 0; j < 2; ++j) {
      const int gn = lh + 2 * j;
      const i32x4 a0 = *reinterpret_cast<const i32x4*>(As + ((ar0 << 2) + (gn ^ sa0)) * 16);
      const i32x4 a1 = *reinterpret_cast<const i32x4*>(As + ((ar1 << 2) + (gn ^ sa1)) * 16);
      const i32x4 b0 = *reinterpret_cast<const i32x4*>(Bs + ((br0 << 2) + (gn ^ sb0)) * 16);
      const i32x4 b1 = *reinterpret_cast<const i32x4*>(Bs + ((br1 << 2) + (gn ^ sb1)) * 16);
      acc00 = MFMA_I8_32(a0, b0, acc00);
      acc01 = MFMA_I8_32(a0, b1, acc01);
      acc10 = MFMA_I8_32(a1, b0, acc10);
      acc11 = MFMA_I8_32(a1, b1, acc11);
    }
    __syncthreads();
    cur ^= 1;
  }

#pragma unroll
  for (int fn = 0; fn < 2; ++fn) {
    const int col = n0 + wn + fn * 32 + l31;
    const float swn = sw[col], bn = bias[col];
#pragma unroll
    for (int fm = 0; fm < 2; ++fm) {
      const i32x16 accv = (fm == 0) ? ((fn == 0) ? acc00 : acc01)
                                    : ((fn == 0) ? acc10 : acc11);
      const int r0 = m0 + wm + fm * 32 + 4 * lh;
#pragma unroll
      for (int reg = 0; reg < 16; ++reg) {
        const int row = r0 + (reg & 3) + 8 * (reg >> 2);
        Y[(size_t)row * kE + col] = (float)accv[reg] * sa[row] * swn + bn;
      }
    }
  }
}

// out-projection GEMM, grid (16,16) = 256 blocks (1/CU); XCD-chunked remap (256 = 8 x 32)
__global__ __launch_bounds__(256) void k_gemm_i8(const int8_t* __restrict__ A,
                                                 const float* __restrict__ sa,
                                                 const int8_t* __restrict__ Bw,
                                                 const float* __restrict__ sw,
                                                 const float* __restrict__ bias,
                                                 float* __restrict__ Y) {
  __shared__ int8_t As[2 * 8192];
  __shared__ int8_t Bs[2 * 8192];
  const int linear = blockIdx.x + (blockIdx.y << 4);
  const int nid = (linear & 7) * 32 + (linear >> 3);
  const int x = nid & 15, y = nid >> 4;
  gemm_i8_body(y * 128, x * 128, A, sa, Bw, sw, bias, Y, As, Bs);
}

// fused Q/K/V projections, grid (16,16,3) = 768 blocks (3/CU); XCD remap (768 = 8 x 96)
__global__ __launch_bounds__(256) void k_gemm_qkv(const int8_t* __restrict__ A,
                                                  const float* __restrict__ sa,
                                                  const int8_t* __restrict__ Wq,
                                                  const int8_t* __restrict__ Wk,
                                                  const int8_t* __restrict__ Wv,
                                                  const float* __restrict__ sWall,
                                                  const float* __restrict__ bq,
                                                  const float* __restrict__ bk,
                                                  const float* __restrict__ bv,
                                                  float* __restrict__ qb,
                                                  float* __restrict__ kb,
                                                  float* __restrict__ vb) {
  __shared__ int8_t As[2 * 8192];
  __shared__ int8_t Bs[2 * 8192];
  const int linear = blockIdx.x + (blockIdx.y << 4) + (blockIdx.z << 8);
  const int nid = (linear & 7) * 96 + (linear >> 3);
  const int x = nid & 15, y = (nid >> 4) & 15, z = nid >> 8;
  const int8_t* Bw = (z == 0) ? Wq : (z == 1) ? Wk : Wv;
  const float* sw = sWall + (size_t)z * kE;
  const float* bias = (z == 0) ? bq : (z == 1) ? bk : bv;
  float* Y = (z == 0) ? qb : (z == 1) ? kb : vb;
  gemm_i8_body(y * 128, x * 128, A, sa, Bw, sw, bias, Y, As, Bs);
}

// ---------------- attention pass 1: 1024 threads, 16 waves = 2 tiles x 4 rowgroups x 2 f-halves ----------------
__global__ __launch_bounds__(1024) void k_attn1(const short* __restrict__ qi,
                                                const short* __restrict__ khi,
                                                const short* __restrict__ klo,
                                                const float* __restrict__ sqg,
                                                float* __restrict__ accPart) {
  const int linear = blockIdx.x + (blockIdx.y << 3);
  const int nid = ((linear & 7) << 6) | (linear >> 3);  // 8 heads per XCD -> K L2-resident
  const int r1 = nid & 7, r2 = 15 - r1, bh = nid >> 3;
  const int b = bh >> 5, h = bh & 31;
  const int tid = threadIdx.x, lane = tid & 63, w = tid >> 6;
  const int g = lane >> 4, c16 = lane & 15;
  const int swz = c16 & 7;
  const int myT = w >> 3;          // 0 -> tile r1, 1 -> tile r2
  const int wl = (w >> 1) & 3;     // rowgroup
  const int fh = w & 1;            // f-half (tokens/rows 0-31 vs 32-63)
  const int myr = myT ? r2 : r1;

  __shared__ short qs[2][64 * 64];
  __shared__ short hbuf[2][64 * 64];
  __shared__ short lbuf[2][64 * 64];
  __shared__ float accT[2][2][1024];
  __shared__ float Arow[128], Crow[128];
  __shared__ float mpart[2][2][64], lpart[2][2][64];

  for (int i = tid; i < 4096; i += 1024) ((float*)accT)[i] = 0.f;

  const int st8 = tid >> 3, su = tid & 7;  // valid for tid < 512 (st8 in [0,64))
  {
    if (tid < 512) {
      const int co = ((su ^ (st8 & 7)) << 3);
      gload16(qi + (size_t)(b * kT + r1 * 64 + st8) * kE + h * 64 + co, &qs[0][st8 * 64 + su * 8]);
      gload16(qi + (size_t)(b * kT + r2 * 64 + st8) * kE + h * 64 + co, &qs[1][st8 * 64 + su * 8]);
    }
  }
  auto stage = [&](int buf, int kt) {
    if (tid < 512) {
      const int tokb = b * kT + kt * 64;
      const size_t gsrc = (size_t)(tokb + st8) * kE + h * 64 + ((su ^ (st8 & 7)) << 3);
      gload16(khi + gsrc, &hbuf[buf][st8 * 64 + su * 8]);
      gload16(klo + gsrc, &lbuf[buf][st8 * 64 + su * 8]);
    }
  };

  stage(0, 0);
  __syncthreads();

  const int qrow = wl * 16 + c16;
  const short* qsp = qs[myT];
  const bf16x8 qf0 = *reinterpret_cast<const bf16x8*>(&qsp[qrow * 64 + ((g ^ swz) << 3)]);
  const bf16x8 qf1 = *reinterpret_cast<const bf16x8*>(&qsp[qrow * 64 + (((4 + g) ^ swz) << 3)]);
  const float Ac = sqg[b * kT + myr * 64 + qrow] * L2E;

  float m = NEG_INF, l = 0.f;
  int cur = 0;

  // ---- phase A: partial row stats over this wave's 32 tokens (f = 2fh, 2fh+1) ----
  for (int kt = 0; kt <= r2; ++kt) {
    if (kt < r2) stage(cur ^ 1, kt + 1);
    if (kt <= myr) {
      float p[2][4];
      float pm = NEG_INF;
#pragma unroll
      for (int fi = 0; fi < 2; ++fi) {
        const int f = 2 * fh + fi;
        const int tokl = f * 16 + c16;
        const bf16x8 ah0 = *reinterpret_cast<const bf16x8*>(&hbuf[cur][tokl * 64 + ((g ^ swz) << 3)]);
        const bf16x8 ah1 = *reinterpret_cast<const bf16x8*>(&hbuf[cur][tokl * 64 + (((4 + g) ^ swz) << 3)]);
        const bf16x8 al0 = *reinterpret_cast<const bf16x8*>(&lbuf[cur][tokl * 64 + ((g ^ swz) << 3)]);
        const bf16x8 al1 = *reinterpret_cast<const bf16x8*>(&lbuf[cur][tokl * 64 + (((4 + g) ^ swz) << 3)]);
        f32x4 sf = {0.f, 0.f, 0.f, 0.f};
        sf = MFMA_BF16(ah0, qf0, sf);
        sf = MFMA_BF16(ah1, qf1, sf);
        sf = MFMA_BF16(al0, qf0, sf);
        sf = MFMA_BF16(al1, qf1, sf);
#pragma unroll
        for (int r = 0; r < 4; ++r) {
          const int tokd = f * 16 + g * 4 + r;
          float s2 = sf[r] * Ac;
          if (kt == myr && tokd > qrow) s2 = NEG_INF;
          p[fi][r] = s2;
          pm = fmaxf(pm, s2);
        }
      }
      pm = fmaxf(pm, __shfl_xor(pm, 16));
      pm = fmaxf(pm, __shfl_xor(pm, 32));
      const bool upd = pm > m + 8.f;
      const float mn = upd ? fmaxf(m, pm) : m;
      const float fsc = fexp2(m - mn);
      float rs = 0.f;
#pragma unroll
      for (int fi = 0; fi < 2; ++fi)
#pragma unroll
        for (int r = 0; r < 4; ++r) rs += fexp2(p[fi][r] - mn);
      rs += __shfl_xor(rs, 16);
      rs += __shfl_xor(rs, 32);
      l = l * fsc + rs;
      m = mn;
    }
    __syncthreads();
    cur ^= 1;
  }

  if (g == 0) {
    mpart[myT][fh][qrow] = m;
    lpart[myT][fh][qrow] = l;
  }
  stage(0, 0);
  __syncthreads();

  // ---- merge partial stats -> Arow / Crow ----
  if (tid < 128) {
    const int tile = tid >> 6, row = tid & 63;
    const int rr = tile ? r2 : r1;
    const float m0 = mpart[tile][0][row], l0 = lpart[tile][0][row];
    const float m1 = mpart[tile][1][row], l1 = lpart[tile][1][row];
    const float mm = fmaxf(m0, m1);
    const float ll = l0 * fexp2(m0 - mm) + l1 * fexp2(m1 - mm);
    Arow[tile * 64 + row] = sqg[b * kT + rr * 64 + row] * L2E;
    Crow[tile * 64 + row] = -(mm + __builtin_amdgcn_logf(ll));
  }
  __syncthreads();

  // ---- phase B: column sums, this wave covers rows f in {2fh, 2fh+1} of its tile ----
  bf16x8 qa0[2], qa1[2];
  float Ar[2][4], Cr[2][4];
#pragma unroll
  for (int fi = 0; fi < 2; ++fi) {
    const int f = 2 * fh + fi;
    const int qr = f * 16 + c16;
    qa0[fi] = *reinterpret_cast<const bf16x8*>(&qsp[qr * 64 + ((g ^ swz) << 3)]);
    qa1[fi] = *reinterpret_cast<const bf16x8*>(&qsp[qr * 64 + (((4 + g) ^ swz) << 3)]);
#pragma unroll
    for (int r = 0; r < 4; ++r) {
      const int tokd = myT * 64 + f * 16 + g * 4 + r;
      Ar[fi][r] = Arow[tokd];
      Cr[fi][r] = Crow[tokd];
    }
  }

  const int ktokL = wl * 16 + c16;
  cur = 0;
  for (int kt = 0; kt <= r2; ++kt) {
    if (kt < r2) stage(cur ^ 1, kt + 1);
    if (kt <= myr) {
      const bf16x8 kh0 = *reinterpret_cast<const bf16x8*>(&hbuf[cur][ktokL * 64 + ((g ^ swz) << 3)]);
      const bf16x8 kh1 = *reinterpret_cast<const bf16x8*>(&hbuf[cur][ktokL * 64 + (((4 + g) ^ swz) << 3)]);
      const bf16x8 kl0 = *reinterpret_cast<const bf16x8*>(&lbuf[cur][ktokL * 64 + ((g ^ swz) << 3)]);
      const bf16x8 kl1 = *reinterpret_cast<const bf16x8*>(&lbuf[cur][ktokL * 64 + (((4 + g) ^ swz) << 3)]);
      float csum = 0.f;
      if (kt < myr) {
#pragma unroll
        for (int fi = 0; fi < 2; ++fi) {
          f32x4 sf = {0.f, 0.f, 0.f, 0.f};
          sf = MFMA_BF16(qa0[fi], kh0, sf);
          sf = MFMA_BF16(qa1[fi], kh1, sf);
          sf = MFMA_BF16(qa0[fi], kl0, sf);
          sf = MFMA_BF16(qa1[fi], kl1, sf);
#pragma unroll
          for (int r = 0; r < 4; ++r) csum += fexp2(fmaf(sf[r], Ar[fi][r], Cr[fi][r]));
        }
      } else {
#pragma unroll
        for (int fi = 0; fi < 2; ++fi) {
          const int f = 2 * fh + fi;
          f32x4 sf = {0.f, 0.f, 0.f, 0.f};
          sf = MFMA_BF16(qa0[fi], kh0, sf);
          sf = MFMA_BF16(qa1[fi], kh1, sf);
          sf = MFMA_BF16(qa0[fi], kl0, sf);
          sf = MFMA_BF16(qa1[fi], kl1, sf);
#pragma unroll
          for (int r = 0; r < 4; ++r) {
            const float v = fexp2(fmaf(sf[r], Ar[fi][r], Cr[fi][r]));
            if (ktokL <= (f * 16 + g * 4 + r)) csum += v;
          }
        }
      }
      csum += __shfl_xor(csum, 16);
      csum += __shfl_xor(csum, 32);
      if (g == 0) accT[myT][fh][kt * 64 + ktokL] += csum;
    }
    __syncthreads();
    cur ^= 1;
  }

  {
    const int i = tid;
    accPart[(size_t)(bh * 8 + r1) * 1024 + i] =
        (accT[0][0][i] + accT[0][1][i]) + (accT[1][0][i] + accT[1][1][i]);
  }
}

// ---------------- merged accreduce + topk (grid 4, 1024 threads) ----------------
__global__ __launch_bounds__(1024) void k_acctopk(const float* __restrict__ part,
                                                  int* __restrict__ sel) {
  const int t = threadIdx.x;
  const int i = t & 255;
  const int sub = t >> 8;  // 0..3
  const int j = blockIdx.x * 256 + i;
  float s = 0.f;
  const int p0 = sub * 128;
  for (int p = p0; p < p0 + 128; ++p) s += part[(size_t)p * 1024 + j];
  __shared__ float partial[4][256];
  __shared__ float v[256];
  partial[sub][i] = s;
  __syncthreads();
  if (sub == 0) {
    const float tot = ((partial[0][i] + partial[1][i]) + partial[2][i]) + partial[3][i];
    v[i] = tot / (float)(kT - j) / 64.f;
  }
  __syncthreads();
  if (sub == 0) {
    const float vi = v[i];
    int rank = 0;
    for (int jj = 0; jj < 256; ++jj) {
      const float vj = v[jj];
      rank += (vj > vi) || (vj == vi && jj < i);
    }
    sel[j] = (rank < 128) ? 1 : 0;
  }
}

// ---------------- attention pass 2: 512 threads, waves 0-3 tile r1, 4-7 tile r2 ----------------
__global__ __launch_bounds__(512) void k_attn2(const short* __restrict__ qi,
                                               const short* __restrict__ ki,
                                               const short* __restrict__ vt,
                                               const float* __restrict__ sqg,
                                               const float* __restrict__ skg,
                                               const unsigned* __restrict__ vmax,
                                               float* __restrict__ ctx) {
  const int linear = blockIdx.x + (blockIdx.y << 3);
  const int nid = ((linear & 7) << 6) | (linear >> 3);  // 8 heads per XCD
  const int r1 = nid & 7, r2 = 15 - r1, bh = nid >> 3;
  const int b = bh >> 5, h = bh & 31;
  const int tid = threadIdx.x, lane = tid & 63, w = tid >> 6;
  const int g = lane >> 4, c16 = lane & 15;
  const int swz = c16 & 7;
  const int myT = w >> 2, wl = w & 3;
  const int myr = myT ? r2 : r1;
  const int wrow = wl * 16 + c16;

  __shared__ short kbuf[2][64 * 64];
  __shared__ short vbuf[2][64 * 64];
  __shared__ float skl[2][64];

  const int qtok = b * kT + myr * 64 + wrow;
  bf16x8 qf[2];
  qf[0] = *reinterpret_cast<const bf16x8*>(qi + (size_t)qtok * kE + h * 64 + g * 8);
  qf[1] = *reinterpret_cast<const bf16x8*>(qi + (size_t)qtok * kE + h * 64 + 32 + g * 8);
  const float sq2 = sqg[qtok] * L2E;
  const float sv = fmaxf(__uint_as_float(*vmax), 1e-5f) / 7.f;

  const int st8 = tid >> 3, su = tid & 7;  // st8 in [0,64)
  auto stage = [&](int buf, int kt) {
    const int tokb = b * kT + kt * 64;
    gload16(ki + (size_t)(tokb + st8) * kE + h * 64 + ((su ^ (st8 & 7)) << 3),
            &kbuf[buf][st8 * 64 + su * 8]);
    gload16(vt + (size_t)(bh * 64 + st8) * kT + kt * 64 + ((su ^ (st8 & 7)) << 3),
            &vbuf[buf][st8 * 64 + su * 8]);
    if (tid < 64) skl[buf][tid] = skg[tokb + tid];
  };

  float m = NEG_INF, l = 0.f;
  f32x4 ot[4];
#pragma unroll
  for (int f = 0; f < 4; ++f) ot[f] = (f32x4){0.f, 0.f, 0.f, 0.f};

  stage(0, 0);
  __syncthreads();
  int cur = 0;

  const int srcLo = c16 | ((g & 1) << 5);
  const int srcHi = srcLo | 16;
  const bool selq = ((g >> 1) & 1) != 0;

  for (int kt = 0; kt <= r2; ++kt) {
    if (kt < r2) stage(cur ^ 1, kt + 1);
    if (kt <= myr) {
      // S^T = K_int @ Q_int^T  (integer-exact)
      f32x4 sf4[4];
#pragma unroll
      for (int f = 0; f < 4; ++f) {
        const int tokl = f * 16 + c16;
        const bf16x8 k0 = *reinterpret_cast<const bf16x8*>(&kbuf[cur][tokl * 64 + ((g ^ swz) << 3)]);
        const bf16x8 k1 = *reinterpret_cast<const bf16x8*>(&kbuf[cur][tokl * 64 + (((4 + g) ^ swz) << 3)]);
        f32x4 s = {0.f, 0.f, 0.f, 0.f};
        s = MFMA_BF16(k0, qf[0], s);
        s = MFMA_BF16(k1, qf[1], s);
        sf4[f] = s;
      }

      float p[4][4];
      float pm = NEG_INF;
#pragma unroll
      for (int f = 0; f < 4; ++f)
#pragma unroll
        for (int r = 0; r < 4; ++r) {
          const int tokd = f * 16 + g * 4 + r;
          float s2 = sf4[f][r] * skl[cur][tokd] * sq2;
          if (kt == myr && tokd > wrow) s2 = NEG_INF;
          p[f][r] = s2;
          pm = fmaxf(pm, s2);
        }
      pm = fmaxf(pm, __shfl_xor(pm, 16));
      pm = fmaxf(pm, __shfl_xor(pm, 32));
      const bool upd = pm > m + 8.f;
      const float mn = upd ? fmaxf(m, pm) : m;
      const float fsc = fexp2(m - mn);
      m = mn;
      float rs = 0.f;
#pragma unroll
      for (int f = 0; f < 4; ++f)
#pragma unroll
        for (int r = 0; r < 4; ++r) {
          const float e = fexp2(p[f][r] - mn);
          p[f][r] = e;
          rs += e;
        }
      rs += __shfl_xor(rs, 16);
      rs += __shfl_xor(rs, 32);
      l = l * fsc + rs;
      if (__any(upd)) {
#pragma unroll
        for (int f = 0; f < 4; ++f)
#pragma unroll
          for (int r = 0; r < 4; ++r) ot[f][r] *= fsc;
      }
#pragma unroll
      for (int c = 0; c < 2; ++c) {
        const unsigned q0a = pk2(p[2 * c][0], p[2 * c][1]);
        const unsigned q0b = pk2(p[2 * c][2], p[2 * c][3]);
        const unsigned q1a = pk2(p[2 * c + 1][0], p[2 * c + 1][1]);
        const unsigned q1b = pk2(p[2 * c + 1][2], p[2 * c + 1][3]);
        unsigned a0, a1;
        union { unsigned u[4]; bf16x8 v; } Bh;
        a0 = __shfl(q0a, srcLo); a1 = __shfl(q1a, srcLo); Bh.u[0] = selq ? a1 : a0;
        a0 = __shfl(q0b, srcLo); a1 = __shfl(q1b, srcLo); Bh.u[1] = selq ? a1 : a0;
        a0 = __shfl(q0a, srcHi); a1 = __shfl(q1a, srcHi); Bh.u[2] = selq ? a1 : a0;
        a0 = __shfl(q0b, srcHi); a1 = __shfl(q1b, srcHi); Bh.u[3] = selq ? a1 : a0;
#pragma unroll
        for (int fd = 0; fd < 4; ++fd) {
          const int d = fd * 16 + c16;
          const bf16x8 va = *reinterpret_cast<const bf16x8*>(
              &vbuf[cur][d * 64 + ((((c << 2) | g) ^ swz) << 3)]);
          ot[fd] = MFMA_BF16(va, Bh.v, ot[fd]);
        }
      }
    }
    __syncthreads();
    cur ^= 1;
  }

  const float il = sv / l;
#pragma unroll
  for (int fd = 0; fd < 4; ++fd) {
    float4 o;
    o.x = ot[fd][0] * il;
    o.y = ot[fd][1] * il;
    o.z = ot[fd][2] * il;
    o.w = ot[fd][3] * il;
    *reinterpret_cast<float4*>(&ctx[(size_t)qtok * kE + h * 64 + fd * 16 + g * 4]) = o;
  }
}

// ---------------- launcher ----------------
extern "C" void kernel_launch(void* const* d_in, const int* in_sizes, int n_in,
                              void* d_out, int out_size, void* d_ws, size_t ws_size,
                              hipStream_t stream) {
  (void)in_sizes; (void)n_in; (void)out_size; (void)ws_size;
  const float* hs = (const float*)d_in[0];
  const float* Wq = (const float*)d_in[2];
  const float* bq = (const float*)d_in[3];
  const float* Wk = (const float*)d_in[4];
  const float* bk = (const float*)d_in[5];
  const float* Wv = (const float*)d_in[6];
  const float* bv = (const float*)d_in[7];
  const float* Wo = (const float*)d_in[8];
  const float* bo = (const float*)d_in[9];
  float* out = (float*)d_out;

  char* p = (char*)d_ws;
  auto take = [&](size_t bytes) {
    char* r = p;
    p += (bytes + 255) & ~(size_t)255;
    return r;
  };
  float* qb  = (float*)take((size_t)2048 * 2048 * 4);  // later khi+klo -> kint+vt
  float* kb  = (float*)take((size_t)2048 * 2048 * 4);
  float* vb  = (float*)take((size_t)2048 * 2048 * 4);
  float* ctx = (float*)take((size_t)2048 * 2048 * 4);  // accPart(2MB) + wq/wk/wv(12MB) alias
  short* qiB = (short*)take((size_t)2048 * 2048 * 2);
  int8_t* xq  = (int8_t*)take((size_t)2048 * 2048);
  int8_t* woq = (int8_t*)take((size_t)2048 * 2048);
  float* sX    = (float*)take(2048 * 4);
  float* sWall = (float*)take(4 * 2048 * 4);
  float* sC    = (float*)take(2048 * 4);
  float* s4v   = (float*)take(2048 * 4);
  float* smix  = (float*)take(1024 * 4);
  int*   sel   = (int*)take(1024 * 4);
  float* sqg   = (float*)take(2048 * 4);
  float* skg   = (float*)take(2048 * 4);
  unsigned* vmax = (unsigned*)take(256);

  // aliases
  short* khi = (short*)qb;
  short* klo = (short*)qb + (size_t)2048 * 2048;
  short* kint = khi;
  short* vtp  = klo;
  float* accPart = ctx;                                  // 512*1024*4 = 2MB
  int8_t* wqq = (int8_t*)ctx + ((size_t)2 << 20);        // weights parked in ctx region
  int8_t* wkq = (int8_t*)ctx + ((size_t)6 << 20);
  int8_t* wvq = (int8_t*)ctx + ((size_t)10 << 20);
  int8_t* cq = xq;

  k_rowquant_all<<<dim3(2048, 5), 256, 0, stream>>>(hs, Wq, Wk, Wv, Wo,
                                                    xq, wqq, wkq, wvq, woq,
                                                    sX, sWall, vmax);

  k_gemm_qkv<<<dim3(16, 16, 3), 256, 0, stream>>>(xq, sX, wqq, wkq, wvq, sWall,
                                                  bq, bk, bv, qb, kb, vb);

  k_prep<<<2048, 256, 0, stream>>>(qb, kb, vb, qiB, sqg, khi, klo, s4v, smix, vmax);

  k_attn1<<<dim3(8, 64), 1024, 0, stream>>>(qiB, khi, klo, sqg, accPart);
  k_acctopk<<<4, 1024, 0, stream>>>(accPart, sel);

  k_kvint<<<3072, 256, 0, stream>>>(kb, s4v, smix, sel, kint, skg, vb, vmax, vtp);

  k_attn2<<<dim3(8, 64), 512, 0, stream>>>(qiB, kint, vtp, sqg, skg, vmax, ctx);

  k_rowquant_i8<<<2048, 256, 0, stream>>>(ctx, cq, sC);
  k_gemm_i8<<<dim3(16, 16), 256, 0, stream>>>(cq, sC, woq, sWall + 3 * 2048, bo, out);
}

// Round 12
// 215.897 us; speedup vs baseline: 1.0310x; 1.0310x over previous
//
#include <hip/hip_runtime.h>
#include <stdint.h>

#define NEG_INF (-__builtin_inff())
#define L2E 1.4426950408889634f

namespace {
constexpr int kT   = 1024;
constexpr int kE   = 2048;
}

using bf16x8 = __attribute__((ext_vector_type(8))) short;
using f32x4  = __attribute__((ext_vector_type(4))) float;
using i32x4  = __attribute__((ext_vector_type(4))) int;
using i32x16 = __attribute__((ext_vector_type(16))) int;

#define MFMA_BF16(a, b, c) __builtin_amdgcn_mfma_f32_16x16x32_bf16((a), (b), (c), 0, 0, 0)
#define MFMA_I8_32(a, b, c) __builtin_amdgcn_mfma_i32_32x32x32_i8((a), (b), (c), 0, 0, 0)

// ---------------- small helpers ----------------
__device__ __forceinline__ void gload16(const void* g, void* l) {
  __builtin_amdgcn_global_load_lds((const __attribute__((address_space(1))) unsigned*)g,
                                   (__attribute__((address_space(3))) unsigned*)l, 16, 0, 0);
}
__device__ __forceinline__ unsigned bfr(float x) {  // f32 -> bf16 bits (RNE)
  unsigned u = __float_as_uint(x);
  return (u + 0x7FFFu + ((u >> 16) & 1u)) >> 16;
}
__device__ __forceinline__ float bf2f(unsigned h) { return __uint_as_float(h << 16); }
__device__ __forceinline__ unsigned pk2(float a, float b) { return bfr(a) | (bfr(b) << 16); }
__device__ __forceinline__ float fexp2(float x) { return __builtin_amdgcn_exp2f(x); }

__device__ __forceinline__ float waveReduceMax(float v) {
#pragma unroll
  for (int o = 32; o > 0; o >>= 1) v = fmaxf(v, __shfl_down(v, o, 64));
  return v;
}
__device__ __forceinline__ float blockMax256(float v, float* r4) {
  const int tid = threadIdx.x;
  float wm = waveReduceMax(v);
  if ((tid & 63) == 0) r4[tid >> 6] = wm;
  __syncthreads();
  float bm = fmaxf(fmaxf(r4[0], r4[1]), fmaxf(r4[2], r4[3]));
  __syncthreads();
  return bm;
}

// ---------------- fused row-quant: hs + 4 weights (grid 2048 x 5) ----------------
__global__ __launch_bounds__(256) void k_rowquant_all(const float* __restrict__ Xh,
                                                      const float* __restrict__ W0,
                                                      const float* __restrict__ W1,
                                                      const float* __restrict__ W2,
                                                      const float* __restrict__ W3,
                                                      int8_t* __restrict__ Qh,
                                                      int8_t* __restrict__ Q0,
                                                      int8_t* __restrict__ Q1,
                                                      int8_t* __restrict__ Q2,
                                                      int8_t* __restrict__ Q3,
                                                      float* __restrict__ sX,
                                                      float* __restrict__ sWall,
                                                      unsigned* __restrict__ vmax) {
  const int y = blockIdx.y;
  const float* X = (y == 0) ? Xh : (y == 1) ? W0 : (y == 2) ? W1 : (y == 3) ? W2 : W3;
  int8_t* Qp = (y == 0) ? Qh : (y == 1) ? Q0 : (y == 2) ? Q1 : (y == 3) ? Q2 : Q3;
  const int row = blockIdx.x;
  const int tid = threadIdx.x;
  if (row == 0 && y == 0 && tid == 0) *vmax = 0u;
  const float* x = X + (size_t)row * kE;
  __shared__ float r4[4];
  float am = 0.f;
  float4 v[2];
#pragma unroll
  for (int it = 0; it < 2; ++it) {
    v[it] = *reinterpret_cast<const float4*>(x + (size_t)(it * 256 + tid) * 4);
    am = fmaxf(am, fmaxf(fmaxf(fabsf(v[it].x), fabsf(v[it].y)), fmaxf(fabsf(v[it].z), fabsf(v[it].w))));
  }
  const float bm = blockMax256(am, r4);
  const float s = fmaxf(bm, 1e-5f) / 127.f;
  int8_t* xq = Qp + (size_t)row * kE;
#pragma unroll
  for (int it = 0; it < 2; ++it) {
    const int i = (it * 256 + tid) * 4;
    char4 q;
    q.x = (char)(int)rintf(v[it].x / s);
    q.y = (char)(int)rintf(v[it].y / s);
    q.z = (char)(int)rintf(v[it].z / s);
    q.w = (char)(int)rintf(v[it].w / s);
    *reinterpret_cast<char4*>(xq + i) = q;
  }
  if (tid == 0) {
    if (y == 0) sX[row] = s;
    else sWall[(y - 1) * kE + row] = s;
  }
}

// final-context row quant
__global__ __launch_bounds__(256) void k_rowquant_i8(const float* __restrict__ X,
                                                     int8_t* __restrict__ Xq,
                                                     float* __restrict__ S) {
  const int row = blockIdx.x;
  const int tid = threadIdx.x;
  const float* x = X + (size_t)row * kE;
  __shared__ float r4[4];
  float am = 0.f;
  float4 v[2];
#pragma unroll
  for (int it = 0; it < 2; ++it) {
    v[it] = *reinterpret_cast<const float4*>(x + (size_t)(it * 256 + tid) * 4);
    am = fmaxf(am, fmaxf(fmaxf(fabsf(v[it].x), fabsf(v[it].y)), fmaxf(fabsf(v[it].z), fabsf(v[it].w))));
  }
  const float bm = blockMax256(am, r4);
  const float s = fmaxf(bm, 1e-5f) / 127.f;
  int8_t* xq = Xq + (size_t)row * kE;
#pragma unroll
  for (int it = 0; it < 2; ++it) {
    const int i = (it * 256 + tid) * 4;
    char4 q;
    q.x = (char)(int)rintf(v[it].x / s);
    q.y = (char)(int)rintf(v[it].y / s);
    q.z = (char)(int)rintf(v[it].z / s);
    q.w = (char)(int)rintf(v[it].w / s);
    *reinterpret_cast<char4*>(xq + i) = q;
  }
  if (tid == 0) S[row] = s;
}

// ---------------- fused prep: q->int-bf16, k->hi/lo split + scales, v absmax ----------------
__global__ __launch_bounds__(256) void k_prep(const float* __restrict__ Qb,
                                              const float* __restrict__ Kb,
                                              const float* __restrict__ Vb,
                                              short* __restrict__ qi,
                                              float* __restrict__ sqg,
                                              short* __restrict__ khi,
                                              short* __restrict__ klo,
                                              float* __restrict__ s4,
                                              float* __restrict__ smix,
                                              unsigned* __restrict__ vmax) {
  const int row = blockIdx.x;
  const int tid = threadIdx.x;
  __shared__ float r4[4];

  {
    const float* x = Qb + (size_t)row * kE;
    float am = 0.f;
    float4 v[2];
#pragma unroll
    for (int it = 0; it < 2; ++it) {
      v[it] = *reinterpret_cast<const float4*>(x + (size_t)(it * 256 + tid) * 4);
      am = fmaxf(am, fmaxf(fmaxf(fabsf(v[it].x), fabsf(v[it].y)), fmaxf(fabsf(v[it].z), fabsf(v[it].w))));
    }
    const float bm = blockMax256(am, r4);
    const float s = fmaxf(bm, 1e-5f) / 127.f;
#pragma unroll
    for (int it = 0; it < 2; ++it) {
      const int i = (it * 256 + tid) * 4;
      short4 q;
      q.x = (short)bfr(rintf(v[it].x / s));
      q.y = (short)bfr(rintf(v[it].y / s));
      q.z = (short)bfr(rintf(v[it].z / s));
      q.w = (short)bfr(rintf(v[it].w / s));
      *reinterpret_cast<short4*>(qi + (size_t)row * kE + i) = q;
    }
    if (tid == 0) sqg[row] = s * 0.125f;
  }

  {
    const float* x = Kb + (size_t)row * kE;
    float am = 0.f;
    float4 v[2];
#pragma unroll
    for (int it = 0; it < 2; ++it) {
      v[it] = *reinterpret_cast<const float4*>(x + (size_t)(it * 256 + tid) * 4);
      am = fmaxf(am, fmaxf(fmaxf(fabsf(v[it].x), fabsf(v[it].y)), fmaxf(fabsf(v[it].z), fabsf(v[it].w))));
    }
    const float bm = blockMax256(am, r4);
#pragma unroll
    for (int it = 0; it < 2; ++it) {
      const int i = (it * 256 + tid) * 4;
      short4 hh, ll;
      unsigned hb;
      hb = bfr(v[it].x); hh.x = (short)hb; ll.x = (short)bfr(v[it].x - bf2f(hb));
      hb = bfr(v[it].y); hh.y = (short)hb; ll.y = (short)bfr(v[it].y - bf2f(hb));
      hb = bfr(v[it].z); hh.z = (short)hb; ll.z = (short)bfr(v[it].z - bf2f(hb));
      hb = bfr(v[it].w); hh.w = (short)hb; ll.w = (short)bfr(v[it].w - bf2f(hb));
      *reinterpret_cast<short4*>(khi + (size_t)row * kE + i) = hh;
      *reinterpret_cast<short4*>(klo + (size_t)row * kE + i) = ll;
    }
    if (tid == 0) {
      s4[row] = fmaxf(bm, 1e-5f) / 7.f;
      if (row < kT) smix[row] = fmaxf(bm / 127.f, 1e-5f);
    }
  }

  {
    const float* x = Vb + (size_t)row * kE;
    float am = 0.f;
#pragma unroll
    for (int it = 0; it < 2; ++it) {
      const float4 v = *reinterpret_cast<const float4*>(x + (size_t)(it * 256 + tid) * 4);
      am = fmaxf(am, fmaxf(fmaxf(fabsf(v.x), fabsf(v.y)), fmaxf(fabsf(v.z), fabsf(v.w))));
    }
    const float bm = blockMax256(am, r4);
    if (tid == 0) atomicMax(vmax, __float_as_uint(bm));
  }
}

// ---------------- merged kint (rows 0..2047) + vint (blocks 2048..3071) ----------------
__global__ __launch_bounds__(256) void k_kvint(const float* __restrict__ Kb,
                                               const float* __restrict__ s4,
                                               const float* __restrict__ smix,
                                               const int* __restrict__ sel,
                                               short* __restrict__ ki,
                                               float* __restrict__ skg,
                                               const float* __restrict__ Vb,
                                               const unsigned* __restrict__ vmax,
                                               short* __restrict__ vt) {
  const int bid = blockIdx.x;
  const int tid = threadIdx.x;
  if (bid < 2048) {
    const int row = bid;
    const int t = row & (kT - 1);
    const float s = sel[t] ? smix[t] : s4[row];
    const float* x = Kb + (size_t)row * kE;
#pragma unroll
    for (int it = 0; it < 2; ++it) {
      const int i = (it * 256 + tid) * 4;
      const float4 v = *reinterpret_cast<const float4*>(x + i);
      short4 q;
      q.x = (short)bfr(rintf(v.x / s));
      q.y = (short)bfr(rintf(v.y / s));
      q.z = (short)bfr(rintf(v.z / s));
      q.w = (short)bfr(rintf(v.w / s));
      *reinterpret_cast<short4*>(ki + (size_t)row * kE + i) = q;
    }
    if (tid == 0) skg[row] = s;
  } else {
    const int t = bid - 2048;
    const int tt = t & 15, bh = t >> 4;
    const int b = bh >> 5, h = bh & 31;
    const float sv = fmaxf(__uint_as_float(*vmax), 1e-5f) / 7.f;
    __shared__ short tr[64][80];
#pragma unroll
    for (int i = 0; i < 4; ++i) {
      const int e = i * 256 + tid;
      const int tok = e >> 4, d4 = (e & 15) * 4;
      const float4 v = *reinterpret_cast<const float4*>(
          &Vb[(size_t)(b * kT + tt * 64 + tok) * kE + h * 64 + d4]);
      tr[d4 + 0][tok] = (short)bfr(rintf(v.x / sv));
      tr[d4 + 1][tok] = (short)bfr(rintf(v.y / sv));
      tr[d4 + 2][tok] = (short)bfr(rintf(v.z / sv));
      tr[d4 + 3][tok] = (short)bfr(rintf(v.w / sv));
    }
    __syncthreads();
#pragma unroll
    for (int i = 0; i < 2; ++i) {
      const int e = i * 256 + tid;
      const int d = e >> 3, u = e & 7;
      const bf16x8 row = *reinterpret_cast<const bf16x8*>(&tr[d][u * 8]);
      *reinterpret_cast<bf16x8*>(&vt[(size_t)(bh * 64 + d) * kT + tt * 64 + u * 8]) = row;
    }
  }
}

// ---------------- int8 MFMA GEMM body: 128x128 tile, 256 threads, 32x32x32 i8 ----------------
__device__ __forceinline__ void gemm_i8_body(int m0, int n0,
                                             const int8_t* __restrict__ A,
                                             const float* __restrict__ sa,
                                             const int8_t* __restrict__ Bw,
                                             const float* __restrict__ sw,
                                             const float* __restrict__ bias,
                                             float* __restrict__ Y,
                                             int8_t* AsBase, int8_t* BsBase) {
  const int tid = threadIdx.x;
  const int lane = tid & 63, w = tid >> 6;
  const int l31 = lane & 31, lh = lane >> 5;
  const int wm = (w >> 1) * 64, wn = (w & 1) * 64;

  const i32x16 zero16 = {0};
  i32x16 acc00 = zero16, acc01 = zero16, acc10 = zero16, acc11 = zero16;

  auto stage = [&](int buf, int k0) {
    int8_t* As = AsBase + buf * 8192;
    int8_t* Bs = BsBase + buf * 8192;
#pragma unroll
    for (int i = 0; i < 2; ++i) {
      const int s = i * 256 + tid;
      const int row = s >> 2, gp = s & 3;
      const int gs = gp ^ ((row >> 1) & 3);
      gload16(A + (size_t)(m0 + row) * kE + k0 + gs * 16, As + s * 16);
    }
#pragma unroll
    for (int i = 0; i < 2; ++i) {
      const int s = i * 256 + tid;
      const int row = s >> 2, gp = s & 3;
      const int gs = gp ^ ((row >> 1) & 3);
      gload16(Bw + (size_t)(n0 + row) * kE + k0 + gs * 16, Bs + s * 16);
    }
  };

  stage(0, 0);
  __syncthreads();
  int cur = 0;

  const int ar0 = wm + l31, ar1 = wm + 32 + l31;
  const int br0 = wn + l31, br1 = wn + 32 + l31;
  const int sa0 = (ar0 >> 1) & 3, sa1 = (ar1 >> 1) & 3;
  const int sb0 = (br0 >> 1) & 3, sb1 = (br1 >> 1) & 3;

  for (int k0 = 0; k0 < kE; k0 += 64) {
    if (k0 + 64 < kE) stage(cur ^ 1, k0 + 64);
    const int8_t* As = AsBase + cur * 8192;
    const int8_t* Bs = BsBase + cur * 8192;
#pragma unroll
    for (int j = 0; j < 2; ++j) {
      const int gn = lh + 2 * j;
      const i32x4 a0 = *reinterpret_cast<const i32x4*>(As + ((ar0 << 2) + (gn ^ sa0)) * 16);
      const i32x4 a1 = *reinterpret_cast<const i32x4*>(As + ((ar1 << 2) + (gn ^ sa1)) * 16);
      const i32x4 b0 = *reinterpret_cast<const i32x4*>(Bs + ((br0 << 2) + (gn ^ sb0)) * 16);
      const i32x4 b1 = *reinterpret_cast<const i32x4*>(Bs + ((br1 << 2) + (gn ^ sb1)) * 16);
      acc00 = MFMA_I8_32(a0, b0, acc00);
      acc01 = MFMA_I8_32(a0, b1, acc01);
      acc10 = MFMA_I8_32(a1, b0, acc10);
      acc11 = MFMA_I8_32(a1, b1, acc11);
    }
    __syncthreads();
    cur ^= 1;
  }

#pragma unroll
  for (int fn = 0; fn < 2; ++fn) {
    const int col = n0 + wn + fn * 32 + l31;
    const float swn = sw[col], bn = bias[col];
#pragma unroll
    for (int fm = 0; fm < 2; ++fm) {
      const i32x16 accv = (fm == 0) ? ((fn == 0) ? acc00 : acc01)
                                    : ((fn == 0) ? acc10 : acc11);
      const int r0 = m0 + wm + fm * 32 + 4 * lh;
#pragma unroll
      for (int reg = 0; reg < 16; ++reg) {
        const int row = r0 + (reg & 3) + 8 * (reg >> 2);
        Y[(size_t)row * kE + col] = (float)accv[reg] * sa[row] * swn + bn;
      }
    }
  }
}

// out-projection GEMM, grid (16,16) = 256 blocks (1/CU); XCD-chunked remap (256 = 8 x 32)
__global__ __launch_bounds__(256) void k_gemm_i8(const int8_t* __restrict__ A,
                                                 const float* __restrict__ sa,
                                                 const int8_t* __restrict__ Bw,
                                                 const float* __restrict__ sw,
                                                 const float* __restrict__ bias,
                                                 float* __restrict__ Y) {
  __shared__ int8_t As[2 * 8192];
  __shared__ int8_t Bs[2 * 8192];
  const int linear = blockIdx.x + (blockIdx.y << 4);
  const int nid = (linear & 7) * 32 + (linear >> 3);
  const int x = nid & 15, y = nid >> 4;
  gemm_i8_body(y * 128, x * 128, A, sa, Bw, sw, bias, Y, As, Bs);
}

// fused Q/K/V projections, grid (16,16,3) = 768 blocks (3/CU); XCD remap (768 = 8 x 96)
__global__ __launch_bounds__(256) void k_gemm_qkv(const int8_t* __restrict__ A,
                                                  const float* __restrict__ sa,
                                                  const int8_t* __restrict__ Wq,
                                                  const int8_t* __restrict__ Wk,
                                                  const int8_t* __restrict__ Wv,
                                                  const float* __restrict__ sWall,
                                                  const float* __restrict__ bq,
                                                  const float* __restrict__ bk,
                                                  const float* __restrict__ bv,
                                                  float* __restrict__ qb,
                                                  float* __restrict__ kb,
                                                  float* __restrict__ vb) {
  __shared__ int8_t As[2 * 8192];
  __shared__ int8_t Bs[2 * 8192];
  const int linear = blockIdx.x + (blockIdx.y << 4) + (blockIdx.z << 8);
  const int nid = (linear & 7) * 96 + (linear >> 3);
  const int x = nid & 15, y = (nid >> 4) & 15, z = nid >> 8;
  const int8_t* Bw = (z == 0) ? Wq : (z == 1) ? Wk : Wv;
  const float* sw = sWall + (size_t)z * kE;
  const float* bias = (z == 0) ? bq : (z == 1) ? bk : bv;
  float* Y = (z == 0) ? qb : (z == 1) ? kb : vb;
  gemm_i8_body(y * 128, x * 128, A, sa, Bw, sw, bias, Y, As, Bs);
}

// ---------------- attention pass 1: 512 threads, waves 0-3 own tile r1, 4-7 own r2 ----------------
__global__ __launch_bounds__(512) void k_attn1(const short* __restrict__ qi,
                                               const short* __restrict__ khi,
                                               const short* __restrict__ klo,
                                               const float* __restrict__ sqg,
                                               float* __restrict__ accPart) {
  const int linear = blockIdx.x + (blockIdx.y << 3);
  const int nid = ((linear & 7) << 6) | (linear >> 3);  // 8 heads per XCD -> K L2-resident
  const int r1 = nid & 7, r2 = 15 - r1, bh = nid >> 3;
  const int b = bh >> 5, h = bh & 31;
  const int tid = threadIdx.x, lane = tid & 63, w = tid >> 6;
  const int g = lane >> 4, c16 = lane & 15;
  const int swz = c16 & 7;
  const int myT = w >> 2, wl = w & 3;
  const int myr = myT ? r2 : r1;

  __shared__ short qs[2][64 * 64];
  __shared__ short hbuf[2][64 * 64];
  __shared__ short lbuf[2][64 * 64];
  __shared__ float accT[2][1024];
  __shared__ float Arow[128], Crow[128];

  for (int i = tid; i < 2048; i += 512) ((float*)accT)[i] = 0.f;

  const int st8 = tid >> 3, su = tid & 7;  // st8 in [0,64)
  {
    const int co = ((su ^ (st8 & 7)) << 3);
    gload16(qi + (size_t)(b * kT + r1 * 64 + st8) * kE + h * 64 + co, &qs[0][st8 * 64 + su * 8]);
    gload16(qi + (size_t)(b * kT + r2 * 64 + st8) * kE + h * 64 + co, &qs[1][st8 * 64 + su * 8]);
  }
  auto stage = [&](int buf, int kt) {
    const int tokb = b * kT + kt * 64;
    const size_t gsrc = (size_t)(tokb + st8) * kE + h * 64 + ((su ^ (st8 & 7)) << 3);
    gload16(khi + gsrc, &hbuf[buf][st8 * 64 + su * 8]);
    gload16(klo + gsrc, &lbuf[buf][st8 * 64 + su * 8]);
  };

  stage(0, 0);
  __syncthreads();

  const int qrow = wl * 16 + c16;
  const short* qsp = qs[myT];
  const bf16x8 qf0 = *reinterpret_cast<const bf16x8*>(&qsp[qrow * 64 + ((g ^ swz) << 3)]);
  const bf16x8 qf1 = *reinterpret_cast<const bf16x8*>(&qsp[qrow * 64 + (((4 + g) ^ swz) << 3)]);
  const float Ac = sqg[b * kT + myr * 64 + qrow] * L2E;

  float m = NEG_INF, l = 0.f;
  int cur = 0;

  // ---- phase A: row stats (S^T = K*Q), each wave its own tile ----
  for (int kt = 0; kt <= r2; ++kt) {
    if (kt < r2) stage(cur ^ 1, kt + 1);
    if (kt <= myr) {
      float p[4][4];
      float pm = NEG_INF;
#pragma unroll
      for (int f = 0; f < 4; ++f) {
        const int tokl = f * 16 + c16;
        const bf16x8 ah0 = *reinterpret_cast<const bf16x8*>(&hbuf[cur][tokl * 64 + ((g ^ swz) << 3)]);
        const bf16x8 ah1 = *reinterpret_cast<const bf16x8*>(&hbuf[cur][tokl * 64 + (((4 + g) ^ swz) << 3)]);
        const bf16x8 al0 = *reinterpret_cast<const bf16x8*>(&lbuf[cur][tokl * 64 + ((g ^ swz) << 3)]);
        const bf16x8 al1 = *reinterpret_cast<const bf16x8*>(&lbuf[cur][tokl * 64 + (((4 + g) ^ swz) << 3)]);
        f32x4 sf = {0.f, 0.f, 0.f, 0.f};
        sf = MFMA_BF16(ah0, qf0, sf);
        sf = MFMA_BF16(ah1, qf1, sf);
        sf = MFMA_BF16(al0, qf0, sf);
        sf = MFMA_BF16(al1, qf1, sf);
#pragma unroll
        for (int r = 0; r < 4; ++r) {
          const int tokd = f * 16 + g * 4 + r;
          float s2 = sf[r] * Ac;
          if (kt == myr && tokd > qrow) s2 = NEG_INF;
          p[f][r] = s2;
          pm = fmaxf(pm, s2);
        }
      }
      pm = fmaxf(pm, __shfl_xor(pm, 16));
      pm = fmaxf(pm, __shfl_xor(pm, 32));
      const bool upd = pm > m + 8.f;
      const float mn = upd ? fmaxf(m, pm) : m;
      const float fsc = fexp2(m - mn);
      float rs = 0.f;
#pragma unroll
      for (int f = 0; f < 4; ++f)
#pragma unroll
        for (int r = 0; r < 4; ++r) rs += fexp2(p[f][r] - mn);
      rs += __shfl_xor(rs, 16);
      rs += __shfl_xor(rs, 32);
      l = l * fsc + rs;
      m = mn;
    }
    __syncthreads();
    cur ^= 1;
  }

  if (g == 0) {
    Arow[myT * 64 + qrow] = Ac;
    Crow[myT * 64 + qrow] = -(m + __builtin_amdgcn_logf(l));
  }
  stage(0, 0);
  __syncthreads();

  // ---- phase B: column sums (S = Q*K), each wave its own tile, 16 columns ----
  bf16x8 qa0[4], qa1[4];
  float Ar[4][4], Cr[4][4];
#pragma unroll
  for (int f = 0; f < 4; ++f) {
    const int qr = f * 16 + c16;
    qa0[f] = *reinterpret_cast<const bf16x8*>(&qsp[qr * 64 + ((g ^ swz) << 3)]);
    qa1[f] = *reinterpret_cast<const bf16x8*>(&qsp[qr * 64 + (((4 + g) ^ swz) << 3)]);
#pragma unroll
    for (int r = 0; r < 4; ++r) {
      const int tokd = myT * 64 + f * 16 + g * 4 + r;
      Ar[f][r] = Arow[tokd];
      Cr[f][r] = Crow[tokd];
    }
  }

  const int ktokL = wl * 16 + c16;
  cur = 0;
  for (int kt = 0; kt <= r2; ++kt) {
    if (kt < r2) stage(cur ^ 1, kt + 1);
    if (kt <= myr) {
      const bf16x8 kh0 = *reinterpret_cast<const bf16x8*>(&hbuf[cur][ktokL * 64 + ((g ^ swz) << 3)]);
      const bf16x8 kh1 = *reinterpret_cast<const bf16x8*>(&hbuf[cur][ktokL * 64 + (((4 + g) ^ swz) << 3)]);
      const bf16x8 kl0 = *reinterpret_cast<const bf16x8*>(&lbuf[cur][ktokL * 64 + ((g ^ swz) << 3)]);
      const bf16x8 kl1 = *reinterpret_cast<const bf16x8*>(&lbuf[cur][ktokL * 64 + (((4 + g) ^ swz) << 3)]);
      float csum = 0.f;
      if (kt < myr) {
#pragma unroll
        for (int f = 0; f < 4; ++f) {
          f32x4 sf = {0.f, 0.f, 0.f, 0.f};
          sf = MFMA_BF16(qa0[f], kh0, sf);
          sf = MFMA_BF16(qa1[f], kh1, sf);
          sf = MFMA_BF16(qa0[f], kl0, sf);
          sf = MFMA_BF16(qa1[f], kl1, sf);
#pragma unroll
          for (int r = 0; r < 4; ++r) csum += fexp2(fmaf(sf[r], Ar[f][r], Cr[f][r]));
        }
      } else {
#pragma unroll
        for (int f = 0; f < 4; ++f) {
          f32x4 sf = {0.f, 0.f, 0.f, 0.f};
          sf = MFMA_BF16(qa0[f], kh0, sf);
          sf = MFMA_BF16(qa1[f], kh1, sf);
          sf = MFMA_BF16(qa0[f], kl0, sf);
          sf = MFMA_BF16(qa1[f], kl1, sf);
#pragma unroll
          for (int r = 0; r < 4; ++r) {
            const float v = fexp2(fmaf(sf[r], Ar[f][r], Cr[f][r]));
            if (ktokL <= (f * 16 + g * 4 + r)) csum += v;
          }
        }
      }
      csum += __shfl_xor(csum, 16);
      csum += __shfl_xor(csum, 32);
      if (g == 0) accT[myT][kt * 64 + ktokL] += csum;
    }
    __syncthreads();
    cur ^= 1;
  }

  for (int i = tid; i < 1024; i += 512)
    accPart[(size_t)(bh * 8 + r1) * 1024 + i] = accT[0][i] + accT[1][i];
}

// ---------------- merged accreduce + topk (grid 4, 1024 threads) ----------------
__global__ __launch_bounds__(1024) void k_acctopk(const float* __restrict__ part,
                                                  int* __restrict__ sel) {
  const int t = threadIdx.x;
  const int i = t & 255;
  const int sub = t >> 8;  // 0..3
  const int j = blockIdx.x * 256 + i;
  float s = 0.f;
  const int p0 = sub * 128;
  for (int p = p0; p < p0 + 128; ++p) s += part[(size_t)p * 1024 + j];
  __shared__ float partial[4][256];
  __shared__ float v[256];
  partial[sub][i] = s;
  __syncthreads();
  if (sub == 0) {
    const float tot = ((partial[0][i] + partial[1][i]) + partial[2][i]) + partial[3][i];
    v[i] = tot / (float)(kT - j) / 64.f;
  }
  __syncthreads();
  if (sub == 0) {
    const float vi = v[i];
    int rank = 0;
    for (int jj = 0; jj < 256; ++jj) {
      const float vj = v[jj];
      rank += (vj > vi) || (vj == vi && jj < i);
    }
    sel[j] = (rank < 128) ? 1 : 0;
  }
}

// ---------------- attention pass 2: 512 threads, waves 0-3 tile r1, 4-7 tile r2 ----------------
__global__ __launch_bounds__(512) void k_attn2(const short* __restrict__ qi,
                                               const short* __restrict__ ki,
                                               const short* __restrict__ vt,
                                               const float* __restrict__ sqg,
                                               const float* __restrict__ skg,
                                               const unsigned* __restrict__ vmax,
                                               float* __restrict__ ctx) {
  const int linear = blockIdx.x + (blockIdx.y << 3);
  const int nid = ((linear & 7) << 6) | (linear >> 3);  // 8 heads per XCD
  const int r1 = nid & 7, r2 = 15 - r1, bh = nid >> 3;
  const int b = bh >> 5, h = bh & 31;
  const int tid = threadIdx.x, lane = tid & 63, w = tid >> 6;
  const int g = lane >> 4, c16 = lane & 15;
  const int swz = c16 & 7;
  const int myT = w >> 2, wl = w & 3;
  const int myr = myT ? r2 : r1;
  const int wrow = wl * 16 + c16;

  __shared__ short kbuf[2][64 * 64];
  __shared__ short vbuf[2][64 * 64];
  __shared__ float skl[2][64];

  const int qtok = b * kT + myr * 64 + wrow;
  bf16x8 qf[2];
  qf[0] = *reinterpret_cast<const bf16x8*>(qi + (size_t)qtok * kE + h * 64 + g * 8);
  qf[1] = *reinterpret_cast<const bf16x8*>(qi + (size_t)qtok * kE + h * 64 + 32 + g * 8);
  const float sq2 = sqg[qtok] * L2E;
  const float sv = fmaxf(__uint_as_float(*vmax), 1e-5f) / 7.f;

  const int st8 = tid >> 3, su = tid & 7;  // st8 in [0,64)
  auto stage = [&](int buf, int kt) {
    const int tokb = b * kT + kt * 64;
    gload16(ki + (size_t)(tokb + st8) * kE + h * 64 + ((su ^ (st8 & 7)) << 3),
            &kbuf[buf][st8 * 64 + su * 8]);
    gload16(vt + (size_t)(bh * 64 + st8) * kT + kt * 64 + ((su ^ (st8 & 7)) << 3),
            &vbuf[buf][st8 * 64 + su * 8]);
    if (tid < 64) skl[buf][tid] = skg[tokb + tid];
  };

  float m = NEG_INF, l = 0.f;
  f32x4 ot[4];
#pragma unroll
  for (int f = 0; f < 4; ++f) ot[f] = (f32x4){0.f, 0.f, 0.f, 0.f};

  stage(0, 0);
  __syncthreads();
  int cur = 0;

  const int srcLo = c16 | ((g & 1) << 5);
  const int srcHi = srcLo | 16;
  const bool selq = ((g >> 1) & 1) != 0;

  for (int kt = 0; kt <= r2; ++kt) {
    if (kt < r2) stage(cur ^ 1, kt + 1);
    if (kt <= myr) {
      // S^T = K_int @ Q_int^T  (integer-exact)
      f32x4 sf4[4];
#pragma unroll
      for (int f = 0; f < 4; ++f) {
        const int tokl = f * 16 + c16;
        const bf16x8 k0 = *reinterpret_cast<const bf16x8*>(&kbuf[cur][tokl * 64 + ((g ^ swz) << 3)]);
        const bf16x8 k1 = *reinterpret_cast<const bf16x8*>(&kbuf[cur][tokl * 64 + (((4 + g) ^ swz) << 3)]);
        f32x4 s = {0.f, 0.f, 0.f, 0.f};
        s = MFMA_BF16(k0, qf[0], s);
        s = MFMA_BF16(k1, qf[1], s);
        sf4[f] = s;
      }

      float p[4][4];
      float pm = NEG_INF;
#pragma unroll
      for (int f = 0; f < 4; ++f)
#pragma unroll
        for (int r = 0; r < 4; ++r) {
          const int tokd = f * 16 + g * 4 + r;
          float s2 = sf4[f][r] * skl[cur][tokd] * sq2;
          if (kt == myr && tokd > wrow) s2 = NEG_INF;
          p[f][r] = s2;
          pm = fmaxf(pm, s2);
        }
      pm = fmaxf(pm, __shfl_xor(pm, 16));
      pm = fmaxf(pm, __shfl_xor(pm, 32));
      const bool upd = pm > m + 8.f;
      const float mn = upd ? fmaxf(m, pm) : m;
      const float fsc = fexp2(m - mn);
      m = mn;
      float rs = 0.f;
#pragma unroll
      for (int f = 0; f < 4; ++f)
#pragma unroll
        for (int r = 0; r < 4; ++r) {
          const float e = fexp2(p[f][r] - mn);
          p[f][r] = e;
          rs += e;
        }
      rs += __shfl_xor(rs, 16);
      rs += __shfl_xor(rs, 32);
      l = l * fsc + rs;
      if (__any(upd)) {
#pragma unroll
        for (int f = 0; f < 4; ++f)
#pragma unroll
          for (int r = 0; r < 4; ++r) ot[f][r] *= fsc;
      }
#pragma unroll
      for (int c = 0; c < 2; ++c) {
        const unsigned q0a = pk2(p[2 * c][0], p[2 * c][1]);
        const unsigned q0b = pk2(p[2 * c][2], p[2 * c][3]);
        const unsigned q1a = pk2(p[2 * c + 1][0], p[2 * c + 1][1]);
        const unsigned q1b = pk2(p[2 * c + 1][2], p[2 * c + 1][3]);
        unsigned a0, a1;
        union { unsigned u[4]; bf16x8 v; } Bh;
        a0 = __shfl(q0a, srcLo); a1 = __shfl(q1a, srcLo); Bh.u[0] = selq ? a1 : a0;
        a0 = __shfl(q0b, srcLo); a1 = __shfl(q1b, srcLo); Bh.u[1] = selq ? a1 : a0;
        a0 = __shfl(q0a, srcHi); a1 = __shfl(q1a, srcHi); Bh.u[2] = selq ? a1 : a0;
        a0 = __shfl(q0b, srcHi); a1 = __shfl(q1b, srcHi); Bh.u[3] = selq ? a1 : a0;
#pragma unroll
        for (int fd = 0; fd < 4; ++fd) {
          const int d = fd * 16 + c16;
          const bf16x8 va = *reinterpret_cast<const bf16x8*>(
              &vbuf[cur][d * 64 + ((((c << 2) | g) ^ swz) << 3)]);
          ot[fd] = MFMA_BF16(va, Bh.v, ot[fd]);
        }
      }
    }
    __syncthreads();
    cur ^= 1;
  }

  const float il = sv / l;
#pragma unroll
  for (int fd = 0; fd < 4; ++fd) {
    float4 o;
    o.x = ot[fd][0] * il;
    o.y = ot[fd][1] * il;
    o.z = ot[fd][2] * il;
    o.w = ot[fd][3] * il;
    *reinterpret_cast<float4*>(&ctx[(size_t)qtok * kE + h * 64 + fd * 16 + g * 4]) = o;
  }
}

// ---------------- launcher ----------------
extern "C" void kernel_launch(void* const* d_in, const int* in_sizes, int n_in,
                              void* d_out, int out_size, void* d_ws, size_t ws_size,
                              hipStream_t stream) {
  (void)in_sizes; (void)n_in; (void)out_size; (void)ws_size;
  const float* hs = (const float*)d_in[0];
  const float* Wq = (const float*)d_in[2];
  const float* bq = (const float*)d_in[3];
  const float* Wk = (const float*)d_in[4];
  const float* bk = (const float*)d_in[5];
  const float* Wv = (const float*)d_in[6];
  const float* bv = (const float*)d_in[7];
  const float* Wo = (const float*)d_in[8];
  const float* bo = (const float*)d_in[9];
  float* out = (float*)d_out;

  char* p = (char*)d_ws;
  auto take = [&](size_t bytes) {
    char* r = p;
    p += (bytes + 255) & ~(size_t)255;
    return r;
  };
  float* qb  = (float*)take((size_t)2048 * 2048 * 4);  // later khi+klo -> kint+vt
  float* kb  = (float*)take((size_t)2048 * 2048 * 4);
  float* vb  = (float*)take((size_t)2048 * 2048 * 4);
  float* ctx = (float*)take((size_t)2048 * 2048 * 4);  // accPart(2MB) + wq/wk/wv(12MB) alias
  short* qiB = (short*)take((size_t)2048 * 2048 * 2);
  int8_t* xq  = (int8_t*)take((size_t)2048 * 2048);
  int8_t* woq = (int8_t*)take((size_t)2048 * 2048);
  float* sX    = (float*)take(2048 * 4);
  float* sWall = (float*)take(4 * 2048 * 4);
  float* sC    = (float*)take(2048 * 4);
  float* s4v   = (float*)take(2048 * 4);
  float* smix  = (float*)take(1024 * 4);
  int*   sel   = (int*)take(1024 * 4);
  float* sqg   = (float*)take(2048 * 4);
  float* skg   = (float*)take(2048 * 4);
  unsigned* vmax = (unsigned*)take(256);

  // aliases
  short* khi = (short*)qb;
  short* klo = (short*)qb + (size_t)2048 * 2048;
  short* kint = khi;
  short* vtp  = klo;
  float* accPart = ctx;                                  // 512*1024*4 = 2MB
  int8_t* wqq = (int8_t*)ctx + ((size_t)2 << 20);        // weights parked in ctx region
  int8_t* wkq = (int8_t*)ctx + ((size_t)6 << 20);
  int8_t* wvq = (int8_t*)ctx + ((size_t)10 << 20);
  int8_t* cq = xq;

  k_rowquant_all<<<dim3(2048, 5), 256, 0, stream>>>(hs, Wq, Wk, Wv, Wo,
                                                    xq, wqq, wkq, wvq, woq,
                                                    sX, sWall, vmax);

  k_gemm_qkv<<<dim3(16, 16, 3), 256, 0, stream>>>(xq, sX, wqq, wkq, wvq, sWall,
                                                  bq, bk, bv, qb, kb, vb);

  k_prep<<<2048, 256, 0, stream>>>(qb, kb, vb, qiB, sqg, khi, klo, s4v, smix, vmax);

  k_attn1<<<dim3(8, 64), 512, 0, stream>>>(qiB, khi, klo, sqg, accPart);
  k_acctopk<<<4, 1024, 0, stream>>>(accPart, sel);

  k_kvint<<<3072, 256, 0, stream>>>(kb, s4v, smix, sel, kint, skg, vb, vmax, vtp);

  k_attn2<<<dim3(8, 64), 512, 0, stream>>>(qiB, kint, vtp, sqg, skg, vmax, ctx);

  k_rowquant_i8<<<2048, 256, 0, stream>>>(ctx, cq, sC);
  k_gemm_i8<<<dim3(16, 16), 256, 0, stream>>>(cq, sC, woq, sWall + 3 * 2048, bo, out);
}